// Round 1
// 520.865 us; speedup vs baseline: 1.1488x; 1.1488x over previous
//
#include <hip/hip_runtime.h>
#include <stdint.h>

// SpectralConv1d: out[b,s,o,k,c] = per-mode-k complex matmul over i=0..31.
//   out_r = sum_i xr*wr - xi*wi ; out_i = sum_i xr*wi + xi*wr
// x: (8,2048,32,64,2) f32; w: (32,32,64,2) f32; out: (8,2048,32,64,2) f32.
// Min traffic 537 MB -> ~85-100us floor.
//
// v2: v1 (306us) was latency-bound (VALUBusy 26%, HBM 17%, both pipes idle):
// per-i {12 global loads -> wait -> FMA burst} with ~3 waves/SIMD exposed
// ~900cy HBM latency, and the 8 o-group waves re-read the same x rows 8x.
// Fix: double-buffered async LDS staging (global_load_lds width=16) of the
// block's x tile; per-chunk vmcnt(0)+barrier keeps waves phase-locked; x is
// pulled from global exactly once per block.

constexpr int D_IN   = 32;
constexpr int D_OUT  = 32;
constexpr int KMAX   = 64;
constexpr int NPOS   = 8 * 2048;      // b*s flattened
constexpr int POSB   = 8;             // positions per block == waves per block
constexpr int OT     = 4;             // output channels per thread
constexpr int THREADS = 512;          // 64 k-lanes x 8 o-groups
constexpr int IC     = 4;             // i-steps staged per chunk
constexpr int NCHUNK = D_IN / IC;     // 8

typedef __attribute__((address_space(3))) uint32_t lds_u32_t;
typedef __attribute__((address_space(1))) const uint32_t glb_u32_t;

__device__ __forceinline__ void gload16(const float2* g, float2* l) {
    // async global->LDS, 16B per lane; LDS dest = wave-uniform base + lane*16
    __builtin_amdgcn_global_load_lds((glb_u32_t*)g, (lds_u32_t*)l, 16, 0, 0);
}

__global__ __launch_bounds__(THREADS, 4)
void spectral_conv1d_kernel(const float2* __restrict__ x,
                            const float2* __restrict__ w,
                            float2* __restrict__ out) {
    // 2 buffers x (8 pos x 4 i x 64 k) float2 = 2 x 16 KB
    __shared__ float2 xs[2][POSB * IC * KMAX];

    const int tid  = threadIdx.x;
    const int k    = tid & (KMAX - 1);    // lane index == k mode
    const int lane = tid & 63;
    const int wid  = tid >> 6;            // wave id 0..7 == o-group == staged pos
    const int o0   = wid * OT;
    const long posBase = (long)blockIdx.x * POSB;

    float2 acc[POSB][OT];
    #pragma unroll
    for (int p = 0; p < POSB; ++p)
        #pragma unroll
        for (int j = 0; j < OT; ++j) acc[p][j] = make_float2(0.f, 0.f);

    // Staging: wave `wid` stages position posBase+wid. Chunk = 4 i-rows of
    // 512B each, contiguous 2KB in global (i-stride = 64 float2 = 512B).
    // One gload16 covers 2 rows: lanes 0-31 -> row ii, lanes 32-63 -> row ii+1,
    // per-lane global offset (lane&31)*16B within the row; LDS dest linear.
    const float2* xrow = x + (posBase + wid) * (D_IN * KMAX)
                           + (long)(lane >> 5) * KMAX + (lane & 31) * 2;

    #define STAGE(buf, c) do {                                              \
        const float2* s0_ = xrow + (long)(c) * IC * KMAX;                   \
        gload16(s0_,            &xs[buf][(wid * IC + 0) * KMAX]);           \
        gload16(s0_ + 2 * KMAX, &xs[buf][(wid * IC + 2) * KMAX]);           \
    } while (0)

    STAGE(0, 0);
    asm volatile("s_waitcnt vmcnt(0)" ::: "memory");
    __syncthreads();

    for (int c = 0; c < NCHUNK; ++c) {
        const int cur = c & 1;
        if (c + 1 < NCHUNK) STAGE(cur ^ 1, c + 1);   // prefetch next chunk

        const int i0 = c * IC;
        #pragma unroll
        for (int ii = 0; ii < IC; ++ii) {
            float2 wreg[OT];
            #pragma unroll
            for (int j = 0; j < OT; ++j)
                wreg[j] = w[((o0 + j) * D_IN + i0 + ii) * KMAX + k];
            #pragma unroll
            for (int p = 0; p < POSB; ++p) {
                float2 xv = xs[cur][(p * IC + ii) * KMAX + k];
                #pragma unroll
                for (int j = 0; j < OT; ++j) {
                    acc[p][j].x = fmaf(xv.x,  wreg[j].x, acc[p][j].x);
                    acc[p][j].x = fmaf(-xv.y, wreg[j].y, acc[p][j].x);
                    acc[p][j].y = fmaf(xv.x,  wreg[j].y, acc[p][j].y);
                    acc[p][j].y = fmaf(xv.y,  wreg[j].x, acc[p][j].y);
                }
            }
        }

        asm volatile("s_waitcnt vmcnt(0)" ::: "memory");  // staged loads landed
        __syncthreads();                                   // all waves done w/ cur
    }
    #undef STAGE

    float2* ob = out + posBase * (D_OUT * KMAX) + k;
    #pragma unroll
    for (int p = 0; p < POSB; ++p)
        #pragma unroll
        for (int j = 0; j < OT; ++j)
            ob[((long)p * D_OUT + o0 + j) * KMAX] = acc[p][j];
}

extern "C" void kernel_launch(void* const* d_in, const int* in_sizes, int n_in,
                              void* d_out, int out_size, void* d_ws, size_t ws_size,
                              hipStream_t stream) {
    const float2* x = (const float2*)d_in[0];
    const float2* w = (const float2*)d_in[1];
    float2* out     = (float2*)d_out;

    dim3 grid(NPOS / POSB);   // 2048 blocks
    spectral_conv1d_kernel<<<grid, THREADS, 0, stream>>>(x, w, out);
}

// Round 2
// 479.861 us; speedup vs baseline: 1.2470x; 1.0854x over previous
//
#include <hip/hip_runtime.h>
#include <stdint.h>

// SpectralConv1d: out[b,s,o,k,c] = per-mode-k complex matmul over i=0..31.
//   out_r = sum_i xr*wr - xi*wi ; out_i = sum_i xr*wi + xi*wr
// x: (8,2048,32,64,2) f32; w: (32,32,64,2) f32; out: (8,2048,32,64,2) f32.
// Min traffic 537 MB -> ~85-100us floor; FMA issue floor ~55-69us.
//
// v2 (227us): double-buffered global_load_lds staging of x. Post-mortem:
// VALUBusy 28.7% (= issue floor / dur), HBM 2.2 TB/s (35%) -> both pipes
// idle; VGPR_Count=64 showed the compiler kept w loads un-hoisted, so each
// ii-step exposes ~300cy L2 latency on its 4 w loads + ~120cy LDS latency.
// v3: hoist the chunk's 16 w float2 into registers right after the barrier
// (full compute phase of slack), batch the 8 ds_read per ii before the FMA
// block. ~120 VGPR, fits the __launch_bounds__(512,4) cap of 128.

constexpr int D_IN   = 32;
constexpr int D_OUT  = 32;
constexpr int KMAX   = 64;
constexpr int NPOS   = 8 * 2048;      // b*s flattened
constexpr int POSB   = 8;             // positions per block == waves per block
constexpr int OT     = 4;             // output channels per thread
constexpr int THREADS = 512;          // 64 k-lanes x 8 o-groups
constexpr int IC     = 4;             // i-steps staged per chunk
constexpr int NCHUNK = D_IN / IC;     // 8

typedef __attribute__((address_space(3))) uint32_t lds_u32_t;
typedef __attribute__((address_space(1))) const uint32_t glb_u32_t;

__device__ __forceinline__ void gload16(const float2* g, float2* l) {
    // async global->LDS, 16B per lane; LDS dest = wave-uniform base + lane*16
    __builtin_amdgcn_global_load_lds((glb_u32_t*)g, (lds_u32_t*)l, 16, 0, 0);
}

__global__ __launch_bounds__(THREADS, 4)
void spectral_conv1d_kernel(const float2* __restrict__ x,
                            const float2* __restrict__ w,
                            float2* __restrict__ out) {
    // 2 buffers x (8 pos x 4 i x 64 k) float2 = 2 x 16 KB
    __shared__ float2 xs[2][POSB * IC * KMAX];

    const int tid  = threadIdx.x;
    const int k    = tid & (KMAX - 1);    // lane index == k mode
    const int lane = tid & 63;
    const int wid  = tid >> 6;            // wave id 0..7 == o-group == staged pos
    const int o0   = wid * OT;
    const long posBase = (long)blockIdx.x * POSB;

    float2 acc[POSB][OT];
    #pragma unroll
    for (int p = 0; p < POSB; ++p)
        #pragma unroll
        for (int j = 0; j < OT; ++j) acc[p][j] = make_float2(0.f, 0.f);

    // Staging: wave `wid` stages position posBase+wid. Chunk = 4 i-rows of
    // 512B each, contiguous 2KB in global. One gload16 covers 2 rows:
    // lanes 0-31 -> row ii, lanes 32-63 -> row ii+1; LDS dest linear.
    const float2* xrow = x + (posBase + wid) * (D_IN * KMAX)
                           + (long)(lane >> 5) * KMAX + (lane & 31) * 2;
    const float2* wb   = w + (long)o0 * (D_IN * KMAX) + k;

    #define STAGE(buf, c) do {                                              \
        const float2* s0_ = xrow + (long)(c) * IC * KMAX;                   \
        gload16(s0_,            &xs[buf][(wid * IC + 0) * KMAX]);           \
        gload16(s0_ + 2 * KMAX, &xs[buf][(wid * IC + 2) * KMAX]);           \
    } while (0)

    STAGE(0, 0);
    asm volatile("s_waitcnt vmcnt(0)" ::: "memory");
    __syncthreads();

    for (int c = 0; c < NCHUNK; ++c) {
        const int cur = c & 1;
        if (c + 1 < NCHUNK) STAGE(cur ^ 1, c + 1);   // prefetch next chunk

        const int i0 = c * IC;

        // Hoist ALL w loads for this chunk: 16 float2 = 32 VGPR. Issued
        // back-to-back at chunk top -> L2 latency hidden under the FMAs.
        float2 wreg[IC][OT];
        #pragma unroll
        for (int ii = 0; ii < IC; ++ii)
            #pragma unroll
            for (int j = 0; j < OT; ++j)
                wreg[ii][j] = wb[(j * D_IN + i0 + ii) * KMAX];

        #pragma unroll
        for (int ii = 0; ii < IC; ++ii) {
            // Batch the 8 LDS reads before the FMA block: back-to-back
            // ds_read_b64, lgkm latency amortized over the batch.
            float2 xv[POSB];
            #pragma unroll
            for (int p = 0; p < POSB; ++p)
                xv[p] = xs[cur][(p * IC + ii) * KMAX + k];

            #pragma unroll
            for (int p = 0; p < POSB; ++p) {
                #pragma unroll
                for (int j = 0; j < OT; ++j) {
                    acc[p][j].x = fmaf(xv[p].x,  wreg[ii][j].x, acc[p][j].x);
                    acc[p][j].x = fmaf(-xv[p].y, wreg[ii][j].y, acc[p][j].x);
                    acc[p][j].y = fmaf(xv[p].x,  wreg[ii][j].y, acc[p][j].y);
                    acc[p][j].y = fmaf(xv[p].y,  wreg[ii][j].x, acc[p][j].y);
                }
            }
        }

        asm volatile("s_waitcnt vmcnt(0)" ::: "memory");  // staged loads landed
        __syncthreads();                                   // all waves done w/ cur
    }
    #undef STAGE

    float2* ob = out + posBase * (D_OUT * KMAX) + k;
    #pragma unroll
    for (int p = 0; p < POSB; ++p)
        #pragma unroll
        for (int j = 0; j < OT; ++j)
            ob[((long)p * D_OUT + o0 + j) * KMAX] = acc[p][j];
}

extern "C" void kernel_launch(void* const* d_in, const int* in_sizes, int n_in,
                              void* d_out, int out_size, void* d_ws, size_t ws_size,
                              hipStream_t stream) {
    const float2* x = (const float2*)d_in[0];
    const float2* w = (const float2*)d_in[1];
    float2* out     = (float2*)d_out;

    dim3 grid(NPOS / POSB);   // 2048 blocks
    spectral_conv1d_kernel<<<grid, THREADS, 0, stream>>>(x, w, out);
}